// Round 1
// baseline (1014.705 us; speedup 1.0000x reference)
//
#include <hip/hip_runtime.h>

// ChebyshevKAN on MI355X (gfx950).
// Reformulation: einsum(bid,oid->bo) + x@base_w.T  ==  Xaug @ W^T with
//   Xaug[b, i*6+d] = T_{d+1}(tanh(x_i))  (d=0..4),  Xaug[b, i*6+5] = x_i
//   W[o,    i*6+d] = coeff[o,i,d+1]      (d=0..4),  W[o,    i*6+5] = base_w[o,i]
// T0==1 slice folds into bias:  bias'[o] = bias[o] + sum_i coeff[o,i,0].
// GEMMs run bf16 MFMA (16x16x32), fp32 accumulate; all nonlinearity in fp32.

typedef __bf16 bf16x8 __attribute__((ext_vector_type(8)));
typedef float f32x4 __attribute__((ext_vector_type(4)));
typedef unsigned short u16x8 __attribute__((ext_vector_type(8)));

__device__ __forceinline__ unsigned short f2bf(float f) {
    // round-to-nearest-even f32 -> bf16 bits (no NaN inputs here)
    unsigned int u = __float_as_uint(f);
    unsigned int r = (u + 0x7FFFu + ((u >> 16) & 1u)) >> 16;
    return (unsigned short)r;
}

// s -> [T1(u),T2(u),T3(u),T4(u),T5(u), s] with u = tanh(s), as bf16 bits
__device__ __forceinline__ void cheb_pack(float s, unsigned short* o6) {
    float u  = tanhf(s);
    float T1 = u;
    float T2 = 2.f * u * u - 1.f;
    float T3 = 2.f * u * T2 - T1;
    float T4 = 2.f * u * T3 - T2;
    float T5 = 2.f * u * T4 - T3;
    o6[0] = f2bf(T1); o6[1] = f2bf(T2); o6[2] = f2bf(T3);
    o6[3] = f2bf(T4); o6[4] = f2bf(T5); o6[5] = f2bf(s);
}

__device__ __forceinline__ void load_lds16(const void* g, void* l) {
    __builtin_amdgcn_global_load_lds(
        (const __attribute__((address_space(1))) void*)g,
        (__attribute__((address_space(3))) void*)l, 16, 0, 0);
}

// ---------------- prep: weights [O,I,6]+[O,I] -> W[N=O, K=I*6] bf16 ----------
__global__ __launch_bounds__(256) void prep_w_kernel(
    const float* __restrict__ coeff, const float* __restrict__ base_w,
    unsigned short* __restrict__ W, int OI)
{
    int idx = blockIdx.x * 256 + threadIdx.x;
    if (idx >= OI) return;
    const float* c = coeff + (size_t)idx * 6;
    unsigned short w0 = f2bf(c[1]), w1 = f2bf(c[2]), w2 = f2bf(c[3]),
                   w3 = f2bf(c[4]), w4 = f2bf(c[5]), w5 = f2bf(base_w[idx]);
    unsigned int* d = (unsigned int*)(W + (size_t)idx * 6);
    d[0] = w0 | ((unsigned int)w1 << 16);
    d[1] = w2 | ((unsigned int)w3 << 16);
    d[2] = w4 | ((unsigned int)w5 << 16);
}

// bias'[o] = bias[o] + sum_i coeff[o,i,0]   (fp32, block per o)
__global__ __launch_bounds__(256) void prep_bias_kernel(
    const float* __restrict__ coeff, const float* __restrict__ bias,
    float* __restrict__ bp, int I)
{
    int o = blockIdx.x, tid = threadIdx.x;
    float s = 0.f;
    for (int i = tid; i < I; i += 256) s += coeff[((size_t)o * I + i) * 6];
    #pragma unroll
    for (int off = 32; off > 0; off >>= 1) s += __shfl_down(s, off);
    __shared__ float red[4];
    int lane = tid & 63, wv = tid >> 6;
    if (lane == 0) red[wv] = s;
    __syncthreads();
    if (tid == 0) bp[o] = bias[o] + red[0] + red[1] + red[2] + red[3];
}

// ---------------- expand1: x[b,1024] -> Xaug[b,6144] bf16  (block per row) ---
__global__ __launch_bounds__(256) void expand1_kernel(
    const float* __restrict__ x, unsigned short* __restrict__ Xa)
{
    int b = blockIdx.x, tid = threadIdx.x;
    f32x4 xv = *(const f32x4*)(x + (size_t)b * 1024 + tid * 4);
    alignas(16) unsigned short ov[24];
    #pragma unroll
    for (int e = 0; e < 4; e++) cheb_pack(tanhf(xv[e]), ov + e * 6);
    u16x8* dst = (u16x8*)(Xa + (size_t)b * 6144 + tid * 24);
    const u16x8* src = (const u16x8*)ov;
    dst[0] = src[0]; dst[1] = src[1]; dst[2] = src[2];
}

// ------------- LN + SiLU + expand2 fused (block per row of 1024) -------------
__global__ __launch_bounds__(256) void ln_silu_expand_kernel(
    const float* __restrict__ H, const float* __restrict__ gamma,
    const float* __restrict__ beta, unsigned short* __restrict__ Xa)
{
    int b = blockIdx.x, tid = threadIdx.x;
    f32x4 hv = *(const f32x4*)(H + (size_t)b * 1024 + tid * 4);
    float s1 = hv[0] + hv[1] + hv[2] + hv[3];
    float s2 = hv[0]*hv[0] + hv[1]*hv[1] + hv[2]*hv[2] + hv[3]*hv[3];
    #pragma unroll
    for (int off = 32; off > 0; off >>= 1) {
        s1 += __shfl_down(s1, off);
        s2 += __shfl_down(s2, off);
    }
    __shared__ float red[8];
    __shared__ float stats[2];
    int lane = tid & 63, wv = tid >> 6;
    if (lane == 0) { red[wv] = s1; red[4 + wv] = s2; }
    __syncthreads();
    if (tid == 0) {
        float t1 = red[0] + red[1] + red[2] + red[3];
        float t2 = red[4] + red[5] + red[6] + red[7];
        float mu = t1 * (1.f / 1024.f);
        float var = t2 * (1.f / 1024.f) - mu * mu;
        stats[0] = mu;
        stats[1] = rsqrtf(var + 1e-5f);
    }
    __syncthreads();
    float mu = stats[0], rs = stats[1];
    f32x4 g  = *(const f32x4*)(gamma + tid * 4);
    f32x4 bt = *(const f32x4*)(beta  + tid * 4);
    alignas(16) unsigned short ov[24];
    #pragma unroll
    for (int e = 0; e < 4; e++) {
        float y = (hv[e] - mu) * rs * g[e] + bt[e];
        float s = y / (1.f + expf(-y));   // SiLU
        cheb_pack(s, ov + e * 6);
    }
    u16x8* dst = (u16x8*)(Xa + (size_t)b * 6144 + tid * 24);
    const u16x8* src = (const u16x8*)ov;
    dst[0] = src[0]; dst[1] = src[1]; dst[2] = src[2];
}

// ---------------- bf16 GEMM: C[M,N] = A[M,K] * W[N,K]^T + bias ---------------
// m97 structure: 128x128 tile, BK=64, global_load_lds width-16 staging,
// 4 waves each owning a 64x64 quadrant as 4x4 of 16x16x32 MFMAs.
__global__ __launch_bounds__(256) void gemm_kernel(
    const unsigned short* __restrict__ A,   // [M,K] bf16 bits
    const unsigned short* __restrict__ Wt,  // [N,K] bf16 bits
    const float* __restrict__ bias,         // [N]
    float* __restrict__ C,                  // [M,N] fp32
    int M, int N, int K)
{
    __shared__ __align__(16) unsigned short As[128 * 64];
    __shared__ __align__(16) unsigned short Bs[128 * 64];
    const int tid  = threadIdx.x;
    const int lane = tid & 63;
    const int wave = tid >> 6;
    const int ntn  = N >> 7;
    const size_t m0 = (size_t)(blockIdx.x / ntn) << 7;
    const size_t n0 = (size_t)(blockIdx.x % ntn) << 7;
    const int wr = (wave >> 1) * 64;        // wave's 64x64 quadrant
    const int wc = (wave & 1) * 64;
    const int fr = lane & 15;               // MFMA A/B operand row
    const int fk = (lane >> 4) * 8;         // MFMA A/B operand k-offset
    const int srow = tid >> 3;              // staging: row within 32-row stripe
    const int scol = (tid & 7) * 8;         // staging: bf16 col (16B per lane)

    f32x4 acc[4][4];
    #pragma unroll
    for (int i = 0; i < 4; i++)
        #pragma unroll
        for (int j = 0; j < 4; j++) acc[i][j] = f32x4{0.f, 0.f, 0.f, 0.f};

    for (int k0 = 0; k0 < K; k0 += 64) {
        #pragma unroll
        for (int s = 0; s < 4; ++s) {
            const unsigned short* ga = A + (m0 + s * 32 + srow) * K + (k0 + scol);
            load_lds16(ga, &As[(s * 256 + wave * 64) * 8]);
        }
        #pragma unroll
        for (int s = 0; s < 4; ++s) {
            const unsigned short* gb = Wt + (n0 + s * 32 + srow) * K + (k0 + scol);
            load_lds16(gb, &Bs[(s * 256 + wave * 64) * 8]);
        }
        __syncthreads();
        #pragma unroll
        for (int kk = 0; kk < 64; kk += 32) {
            bf16x8 af[4], bfr[4];
            #pragma unroll
            for (int i = 0; i < 4; i++)
                af[i] = *(const bf16x8*)&As[(wr + i * 16 + fr) * 64 + kk + fk];
            #pragma unroll
            for (int j = 0; j < 4; j++)
                bfr[j] = *(const bf16x8*)&Bs[(wc + j * 16 + fr) * 64 + kk + fk];
            #pragma unroll
            for (int i = 0; i < 4; i++)
                #pragma unroll
                for (int j = 0; j < 4; j++)
                    acc[i][j] = __builtin_amdgcn_mfma_f32_16x16x32_bf16(
                        af[i], bfr[j], acc[i][j], 0, 0, 0);
        }
        __syncthreads();
    }

    // C/D layout (verified m89/m91): col = lane&15, row = (lane>>4)*4 + reg
    const int rbase = wr + (lane >> 4) * 4;
    const int cbase = wc + (lane & 15);
    #pragma unroll
    for (int j = 0; j < 4; j++) {
        const int col = (int)n0 + cbase + j * 16;
        const float bv = bias[col];
        #pragma unroll
        for (int i = 0; i < 4; i++) {
            float* cp = C + (m0 + rbase + i * 16) * N + col;
            #pragma unroll
            for (int r = 0; r < 4; r++) cp[(size_t)r * N] = acc[i][j][r] + bv;
        }
    }
}

extern "C" void kernel_launch(void* const* d_in, const int* in_sizes, int n_in,
                              void* d_out, int out_size, void* d_ws, size_t ws_size,
                              hipStream_t stream)
{
    const float* x       = (const float*)d_in[0];
    const float* coeff1  = (const float*)d_in[1];
    const float* base_w1 = (const float*)d_in[2];
    const float* bias1   = (const float*)d_in[3];
    const float* gamma   = (const float*)d_in[4];
    const float* beta    = (const float*)d_in[5];
    const float* coeff2  = (const float*)d_in[6];
    const float* base_w2 = (const float*)d_in[7];
    const float* bias2   = (const float*)d_in[8];
    float* out = (float*)d_out;

    const int B = 16384, D0 = 1024, D1 = 1024, D2 = 512;
    const int K1 = D0 * 6, K2 = D1 * 6;   // 6144 each

    // workspace layout
    char* base = (char*)d_ws;
    size_t off = 0;
    unsigned short* W1 = (unsigned short*)(base + off); off += (size_t)D1 * K1 * 2;
    unsigned short* W2 = (unsigned short*)(base + off); off += (size_t)D2 * K2 * 2;
    float* b1p = (float*)(base + off); off += (size_t)D1 * 4;
    float* b2p = (float*)(base + off); off += (size_t)D2 * 4;
    off = (off + 255) & ~(size_t)255;

    // chunk rows so Xaug (K1 bf16) + h (D1 f32) fit in remaining ws; keep %128
    size_t per_row = (size_t)K1 * 2 + (size_t)D1 * 4;   // 16384 B
    long long avail = (long long)ws_size - (long long)off;
    long long mcl = avail > 0 ? avail / (long long)per_row : 0;
    int Mc = (int)((mcl / 128) * 128);
    if (Mc < 128) Mc = 128;
    if (Mc > B) Mc = B;

    unsigned short* Xa = (unsigned short*)(base + off);
    float* h = (float*)(base + off + (size_t)Mc * K1 * 2);

    prep_w_kernel<<<(D1 * D0 + 255) / 256, 256, 0, stream>>>(coeff1, base_w1, W1, D1 * D0);
    prep_w_kernel<<<(D2 * D1 + 255) / 256, 256, 0, stream>>>(coeff2, base_w2, W2, D2 * D1);
    prep_bias_kernel<<<D1, 256, 0, stream>>>(coeff1, bias1, b1p, D0);
    prep_bias_kernel<<<D2, 256, 0, stream>>>(coeff2, bias2, b2p, D1);

    for (int m0 = 0; m0 < B; m0 += Mc) {
        int rows = (B - m0 < Mc) ? (B - m0) : Mc;
        expand1_kernel<<<rows, 256, 0, stream>>>(x + (size_t)m0 * D0, Xa);
        gemm_kernel<<<(rows / 128) * (D1 / 128), 256, 0, stream>>>(
            Xa, W1, b1p, h, rows, D1, K1);
        ln_silu_expand_kernel<<<rows, 256, 0, stream>>>(h, gamma, beta, Xa);
        gemm_kernel<<<(rows / 128) * (D2 / 128), 256, 0, stream>>>(
            Xa, W2, b2p, out + (size_t)m0 * D2, rows, D2, K2);
    }
}